// Round 2
// baseline (188.140 us; speedup 1.0000x reference)
//
#include <hip/hip_runtime.h>

#define NPTS 100000
#define NJ 24
#define PDIM 64
#define LL 32
#define CC 16
#define JOINT_STRIDE (PDIM*LL*LL*CC)   /* 1<<20 floats */
#define ID_STRIDE (LL*LL*CC)           /* 16384 floats */
#define RB 100                         /* reduce blocks */
#define NCH 192                        /* point chunks per joint-triple */
#define CHUNK ((NPTS + NCH - 1) / NCH) /* 521 */

__global__ __launch_bounds__(256) void k_partial(const float* __restrict__ qp,
                                                 float* __restrict__ partial) {
    __shared__ float sm[3][256];
    int tid = threadIdx.x;
    float s0 = 0.f, s1 = 0.f, s2 = 0.f;
    for (int n = blockIdx.x * 256 + tid; n < NPTS; n += RB * 256) {
        s0 += qp[n * 3 + 0];
        s1 += qp[n * 3 + 1];
        s2 += qp[n * 3 + 2];
    }
    sm[0][tid] = s0; sm[1][tid] = s1; sm[2][tid] = s2;
    __syncthreads();
    for (int s = 128; s > 0; s >>= 1) {
        if (tid < s) {
            sm[0][tid] += sm[0][tid + s];
            sm[1][tid] += sm[1][tid + s];
            sm[2][tid] += sm[2][tid + s];
        }
        __syncthreads();
    }
    if (tid == 0) {
        partial[blockIdx.x * 3 + 0] = sm[0][0];
        partial[blockIdx.x * 3 + 1] = sm[1][0];
        partial[blockIdx.x * 3 + 2] = sm[2][0];
    }
}

__global__ __launch_bounds__(256) void k_final(const float* __restrict__ partial,
                                               const float* __restrict__ scale,
                                               float* __restrict__ mi) {
    __shared__ float sm[3][256];
    int tid = threadIdx.x;
    float s0 = 0.f, s1 = 0.f, s2 = 0.f;
    if (tid < RB) {
        s0 = partial[tid * 3 + 0];
        s1 = partial[tid * 3 + 1];
        s2 = partial[tid * 3 + 2];
    }
    sm[0][tid] = s0; sm[1][tid] = s1; sm[2][tid] = s2;
    __syncthreads();
    for (int s = 128; s > 0; s >>= 1) {
        if (tid < s) {
            sm[0][tid] += sm[0][tid + s];
            sm[1][tid] += sm[1][tid + s];
            sm[2][tid] += sm[2][tid + s];
        }
        __syncthreads();
    }
    if (tid == 0) {
        const float invn = 1.0f / (float)NPTS;
        mi[0] = sm[0][0] * invn;
        mi[1] = sm[1][0] * invn;
        mi[2] = sm[2][0] * invn;
        mi[3] = 1.0f / (scale[0] * 0.5f);
        mi[4] = 1.0f / (scale[1] * 0.5f);
        mi[5] = 1.0f / (scale[2] * 0.5f);
    }
}

/* One block handles joint-triple (trip = bid%8 -> XCD-local 9 slices of 64KB)
   for a chunk of points. lane = 4 channels (float4); 4 lanes per point. */
__global__ __launch_bounds__(256) void k_sample(const float* __restrict__ qp,
                                                const float* __restrict__ px,
                                                const float* __restrict__ py,
                                                const float* __restrict__ pz,
                                                const float* __restrict__ mi,
                                                const int* __restrict__ idp,
                                                float* __restrict__ out) {
    const int bid   = blockIdx.x;
    const int trip  = bid & 7;      /* joint triple 0..7 -> XCD class */
    const int chunk = bid >> 3;     /* 0..NCH-1 */
    const int tid   = threadIdx.x;
    const int pl    = tid >> 2;     /* local point 0..63 */
    const int cq    = tid & 3;      /* channel quad 0..3 */

    const int id  = *idp;
    const size_t sid = (size_t)id * ID_STRIDE;
    const int jbase = trip * 3;

    const float m0 = mi[0], m1 = mi[1], m2 = mi[2];
    const float i0 = mi[3], i1 = mi[4], i2 = mi[5];

    const int p0 = chunk * CHUNK;
    const int p1 = min(p0 + CHUNK, NPTS);

    for (int p = p0 + pl; p < p1; p += 64) {
        const float cx = (qp[p * 3 + 0] - m0) * i0;
        const float cy = (qp[p * 3 + 1] - m1) * i1;
        const float cz = (qp[p * 3 + 2] - m2) * i2;

        float4* outp = (float4*)(out + (size_t)p * (NJ * 3 * CC));

#pragma unroll
        for (int plane = 0; plane < 3; ++plane) {
            const float* pbase = (plane == 0 ? px : plane == 1 ? py : pz);
            const float gx = (plane == 0 ? cy : plane == 1 ? cz : cx); /* W index */
            const float gy = (plane == 0 ? cx : plane == 1 ? cy : cz); /* H index */

            float fx = fminf(fmaxf((gx + 1.0f) * (0.5f * (LL - 1)), 0.0f), (float)(LL - 1));
            float fy = fminf(fmaxf((gy + 1.0f) * (0.5f * (LL - 1)), 0.0f), (float)(LL - 1));
            int x0 = (int)fx, y0 = (int)fy;
            float wx = fx - (float)x0, wy = fy - (float)y0;
            int x1 = min(x0 + 1, LL - 1), y1 = min(y0 + 1, LL - 1);
            float w00 = (1.f - wx) * (1.f - wy);
            float w01 = wx * (1.f - wy);
            float w10 = (1.f - wx) * wy;
            float w11 = wx * wy;

            /* float4 indices within one 32x32x16 slice */
            const int q00 = (y0 * LL + x0) * 4 + cq;
            const int q01 = (y0 * LL + x1) * 4 + cq;
            const int q10 = (y1 * LL + x0) * 4 + cq;
            const int q11 = (y1 * LL + x1) * 4 + cq;

#pragma unroll
            for (int jj = 0; jj < 3; ++jj) {
                const int j = jbase + jj;
                const float4* b4 = (const float4*)(pbase + sid + (size_t)j * JOINT_STRIDE);
                const float4 g00 = b4[q00];
                const float4 g01 = b4[q01];
                const float4 g10 = b4[q10];
                const float4 g11 = b4[q11];
                float4 r;
                r.x = w00 * g00.x + w01 * g01.x + w10 * g10.x + w11 * g11.x;
                r.y = w00 * g00.y + w01 * g01.y + w10 * g10.y + w11 * g11.y;
                r.z = w00 * g00.z + w01 * g01.z + w10 * g10.z + w11 * g11.z;
                r.w = w00 * g00.w + w01 * g01.w + w10 * g10.w + w11 * g11.w;
                outp[(j * 3 + plane) * 4 + cq] = r;
            }
        }
    }
}

extern "C" void kernel_launch(void* const* d_in, const int* in_sizes, int n_in,
                              void* d_out, int out_size, void* d_ws, size_t ws_size,
                              hipStream_t stream) {
    const int*   idp   = (const int*)d_in[0];
    const float* qp    = (const float*)d_in[1];
    const float* scale = (const float*)d_in[2];
    const float* px    = (const float*)d_in[3];
    const float* py    = (const float*)d_in[4];
    const float* pz    = (const float*)d_in[5];
    float* out = (float*)d_out;
    float* ws  = (float*)d_ws;

    /* ws layout: [0,300) partials, [384,390) mean+inv_scale */
    k_partial<<<RB, 256, 0, stream>>>(qp, ws);
    k_final<<<1, 256, 0, stream>>>(ws, scale, ws + 384);
    k_sample<<<NCH * 8, 256, 0, stream>>>(qp, px, py, pz, ws + 384, idp, out);
}

// Round 4
// 158.576 us; speedup vs baseline: 1.1864x; 1.1864x over previous
//
#include <hip/hip_runtime.h>

#define NPTS 100000
#define NJ 24
#define PDIM 64
#define LL 32
#define CC 16
#define JOINT_STRIDE (PDIM*LL*LL*CC)   /* 1<<20 floats */
#define J4 (JOINT_STRIDE/4)            /* float4 stride per joint */
#define ID_STRIDE (LL*LL*CC)           /* 16384 floats */
#define RB 100                         /* reduce blocks */
#define PPB 64                         /* points per block */

typedef float f32x4 __attribute__((ext_vector_type(4)));

__global__ __launch_bounds__(256) void k_partial(const float* __restrict__ qp,
                                                 float* __restrict__ partial) {
    __shared__ float sm[3][256];
    int tid = threadIdx.x;
    float s0 = 0.f, s1 = 0.f, s2 = 0.f;
    for (int n = blockIdx.x * 256 + tid; n < NPTS; n += RB * 256) {
        s0 += qp[n * 3 + 0];
        s1 += qp[n * 3 + 1];
        s2 += qp[n * 3 + 2];
    }
    sm[0][tid] = s0; sm[1][tid] = s1; sm[2][tid] = s2;
    __syncthreads();
    for (int s = 128; s > 0; s >>= 1) {
        if (tid < s) {
            sm[0][tid] += sm[0][tid + s];
            sm[1][tid] += sm[1][tid + s];
            sm[2][tid] += sm[2][tid + s];
        }
        __syncthreads();
    }
    if (tid == 0) {
        partial[blockIdx.x * 3 + 0] = sm[0][0];
        partial[blockIdx.x * 3 + 1] = sm[1][0];
        partial[blockIdx.x * 3 + 2] = sm[2][0];
    }
}

__global__ __launch_bounds__(256) void k_final(const float* __restrict__ partial,
                                               const float* __restrict__ scale,
                                               float* __restrict__ mi) {
    __shared__ float sm[3][256];
    int tid = threadIdx.x;
    float s0 = 0.f, s1 = 0.f, s2 = 0.f;
    if (tid < RB) {
        s0 = partial[tid * 3 + 0];
        s1 = partial[tid * 3 + 1];
        s2 = partial[tid * 3 + 2];
    }
    sm[0][tid] = s0; sm[1][tid] = s1; sm[2][tid] = s2;
    __syncthreads();
    for (int s = 128; s > 0; s >>= 1) {
        if (tid < s) {
            sm[0][tid] += sm[0][tid + s];
            sm[1][tid] += sm[1][tid + s];
            sm[2][tid] += sm[2][tid + s];
        }
        __syncthreads();
    }
    if (tid == 0) {
        const float invn = 1.0f / (float)NPTS;
        mi[0] = sm[0][0] * invn;
        mi[1] = sm[1][0] * invn;
        mi[2] = sm[2][0] * invn;
        mi[3] = 1.0f / (scale[0] * 0.5f);
        mi[4] = 1.0f / (scale[1] * 0.5f);
        mi[5] = 1.0f / (scale[2] * 0.5f);
    }
}

/* thread = (point, channel-quad). 64 points per 256-thread block.
   All 24 joints x 3 planes per thread; float4 gathers from cached grids,
   non-temporal float4 stores of the full contiguous output row. */
__global__ __launch_bounds__(256) void k_sample(const float* __restrict__ qp,
                                                const float* __restrict__ px,
                                                const float* __restrict__ py,
                                                const float* __restrict__ pz,
                                                const float* __restrict__ mi,
                                                const int* __restrict__ idp,
                                                float* __restrict__ out) {
    const int tid = threadIdx.x;
    const int pl  = tid >> 2;   /* local point 0..63 */
    const int cq  = tid & 3;    /* channel quad 0..3 */
    const int p   = blockIdx.x * PPB + pl;
    if (p >= NPTS) return;

    const int id = *idp;
    const size_t sid = (size_t)id * ID_STRIDE;

    const float m0 = mi[0], m1 = mi[1], m2 = mi[2];
    const float i0 = mi[3], i1 = mi[4], i2 = mi[5];

    const float cx = (qp[p * 3 + 0] - m0) * i0;
    const float cy = (qp[p * 3 + 1] - m1) * i1;
    const float cz = (qp[p * 3 + 2] - m2) * i2;

    /* plane 0 (feat_x): gx=cy (W), gy=cx (H)
       plane 1 (feat_y): gx=cz,     gy=cy
       plane 2 (feat_z): gx=cx,     gy=cz  */
    const float gxs[3] = {cy, cz, cx};
    const float gys[3] = {cx, cy, cz};
    const f32x4* base4[3] = {(const f32x4*)(px + sid),
                             (const f32x4*)(py + sid),
                             (const f32x4*)(pz + sid)};

    float w00[3], w01[3], w10[3], w11[3];
    int   q00[3], q01[3], q10[3], q11[3];
#pragma unroll
    for (int pn = 0; pn < 3; ++pn) {
        float fx = fminf(fmaxf((gxs[pn] + 1.0f) * (0.5f * (LL - 1)), 0.0f), (float)(LL - 1));
        float fy = fminf(fmaxf((gys[pn] + 1.0f) * (0.5f * (LL - 1)), 0.0f), (float)(LL - 1));
        int x0 = (int)fx, y0 = (int)fy;
        float wx = fx - (float)x0, wy = fy - (float)y0;
        int x1 = min(x0 + 1, LL - 1), y1 = min(y0 + 1, LL - 1);
        w00[pn] = (1.f - wx) * (1.f - wy);
        w01[pn] = wx * (1.f - wy);
        w10[pn] = (1.f - wx) * wy;
        w11[pn] = wx * wy;
        q00[pn] = (y0 * LL + x0) * 4 + cq;
        q01[pn] = (y0 * LL + x1) * 4 + cq;
        q10[pn] = (y1 * LL + x0) * 4 + cq;
        q11[pn] = (y1 * LL + x1) * 4 + cq;
    }

    f32x4* outp = (f32x4*)(out + (size_t)p * (NJ * 3 * CC));

#pragma unroll 4
    for (int j = 0; j < NJ; ++j) {
#pragma unroll
        for (int pn = 0; pn < 3; ++pn) {
            const f32x4* b4 = base4[pn] + (size_t)j * J4;
            const f32x4 g00 = b4[q00[pn]];
            const f32x4 g01 = b4[q01[pn]];
            const f32x4 g10 = b4[q10[pn]];
            const f32x4 g11 = b4[q11[pn]];
            f32x4 r = w00[pn] * g00 + w01[pn] * g01 + w10[pn] * g10 + w11[pn] * g11;
            __builtin_nontemporal_store(r, &outp[(j * 3 + pn) * 4 + cq]);
        }
    }
}

extern "C" void kernel_launch(void* const* d_in, const int* in_sizes, int n_in,
                              void* d_out, int out_size, void* d_ws, size_t ws_size,
                              hipStream_t stream) {
    const int*   idp   = (const int*)d_in[0];
    const float* qp    = (const float*)d_in[1];
    const float* scale = (const float*)d_in[2];
    const float* px    = (const float*)d_in[3];
    const float* py    = (const float*)d_in[4];
    const float* pz    = (const float*)d_in[5];
    float* out = (float*)d_out;
    float* ws  = (float*)d_ws;

    /* ws layout: [0,300) partials, [384,390) mean+inv_scale */
    k_partial<<<RB, 256, 0, stream>>>(qp, ws);
    k_final<<<1, 256, 0, stream>>>(ws, scale, ws + 384);
    k_sample<<<(NPTS + PPB - 1) / PPB, 256, 0, stream>>>(qp, px, py, pz, ws + 384, idp, out);
}

// Round 5
// 125.535 us; speedup vs baseline: 1.4987x; 1.2632x over previous
//
#include <hip/hip_runtime.h>

#define NPTS 100000
#define NJ 24
#define PDIM 64
#define LL 32
#define CC 16
#define JOINT_STRIDE (PDIM*LL*LL*CC)   /* 1<<20 floats = 4 MB per joint */
#define J4 (JOINT_STRIDE/4)            /* float4 stride per joint */
#define ID_STRIDE (LL*LL*CC)           /* 16384 floats = 64 KB slice */
#define RB 100                         /* reduce blocks */
#define PPW 4                          /* points per wave */
#define PPB 16                         /* points per block (4 waves) */

typedef float f32x4 __attribute__((ext_vector_type(4)));

__global__ __launch_bounds__(256) void k_partial(const float* __restrict__ qp,
                                                 float* __restrict__ partial) {
    __shared__ float sm[3][256];
    int tid = threadIdx.x;
    float s0 = 0.f, s1 = 0.f, s2 = 0.f;
    for (int n = blockIdx.x * 256 + tid; n < NPTS; n += RB * 256) {
        s0 += qp[n * 3 + 0];
        s1 += qp[n * 3 + 1];
        s2 += qp[n * 3 + 2];
    }
    sm[0][tid] = s0; sm[1][tid] = s1; sm[2][tid] = s2;
    __syncthreads();
    for (int s = 128; s > 0; s >>= 1) {
        if (tid < s) {
            sm[0][tid] += sm[0][tid + s];
            sm[1][tid] += sm[1][tid + s];
            sm[2][tid] += sm[2][tid + s];
        }
        __syncthreads();
    }
    if (tid == 0) {
        partial[blockIdx.x * 3 + 0] = sm[0][0];
        partial[blockIdx.x * 3 + 1] = sm[1][0];
        partial[blockIdx.x * 3 + 2] = sm[2][0];
    }
}

__global__ __launch_bounds__(256) void k_final(const float* __restrict__ partial,
                                               const float* __restrict__ scale,
                                               float* __restrict__ mi) {
    __shared__ float sm[3][256];
    int tid = threadIdx.x;
    float s0 = 0.f, s1 = 0.f, s2 = 0.f;
    if (tid < RB) {
        s0 = partial[tid * 3 + 0];
        s1 = partial[tid * 3 + 1];
        s2 = partial[tid * 3 + 2];
    }
    sm[0][tid] = s0; sm[1][tid] = s1; sm[2][tid] = s2;
    __syncthreads();
    for (int s = 128; s > 0; s >>= 1) {
        if (tid < s) {
            sm[0][tid] += sm[0][tid + s];
            sm[1][tid] += sm[1][tid + s];
            sm[2][tid] += sm[2][tid + s];
        }
        __syncthreads();
    }
    if (tid == 0) {
        const float invn = 1.0f / (float)NPTS;
        mi[0] = sm[0][0] * invn;
        mi[1] = sm[1][0] * invn;
        mi[2] = sm[2][0] * invn;
        mi[3] = 1.0f / (scale[0] * 0.5f);
        mi[4] = 1.0f / (scale[1] * 0.5f);
        mi[5] = 1.0f / (scale[2] * 0.5f);
    }
}

/* wave = 4 points; lane = (pt, jg, cq): pt=lane>>4, jg=(lane>>2)&3, cq=lane&3.
   Per load instruction: one corner, 4 pts x 4 joints x 4ch float4 = 1 KB.
   Corner weights/offsets are lane-resident -> reduction is lane-local.
   Stores: 1 KB nt float4, full 64B lines, immediate offsets off one vaddr. */
__global__ __launch_bounds__(256) void k_sample(const float* __restrict__ qp,
                                                const float* __restrict__ px,
                                                const float* __restrict__ py,
                                                const float* __restrict__ pz,
                                                const float* __restrict__ mi,
                                                const int* __restrict__ idp,
                                                float* __restrict__ out) {
    const int tid  = threadIdx.x;
    const int wv   = tid >> 6;
    const int lane = tid & 63;
    const int pt   = lane >> 4;
    const int jg   = (lane >> 2) & 3;
    const int cq   = lane & 3;
    const int p    = blockIdx.x * PPB + wv * PPW + pt;   /* always < NPTS (6250*16) */

    const int id = *idp;
    const size_t sid = (size_t)id * ID_STRIDE;

    const float m0 = mi[0], m1 = mi[1], m2 = mi[2];
    const float i0 = mi[3], i1 = mi[4], i2 = mi[5];

    const float cx = (qp[p * 3 + 0] - m0) * i0;
    const float cy = (qp[p * 3 + 1] - m1) * i1;
    const float cz = (qp[p * 3 + 2] - m2) * i2;

    /* plane 0 (feat_x): gx=cy (W), gy=cx (H)
       plane 1 (feat_y): gx=cz,     gy=cy
       plane 2 (feat_z): gx=cx,     gy=cz  */
    const float gxs[3] = {cy, cz, cx};
    const float gys[3] = {cx, cy, cz};
    const f32x4* base4[3] = {(const f32x4*)(px + sid),
                             (const f32x4*)(py + sid),
                             (const f32x4*)(pz + sid)};

    float w00[3], w01[3], w10[3], w11[3];
    int   v00[3], v01[3], v10[3], v11[3];   /* per-lane f32x4 offsets: jg joint + corner + cq */
#pragma unroll
    for (int pn = 0; pn < 3; ++pn) {
        float fx = fminf(fmaxf((gxs[pn] + 1.0f) * (0.5f * (LL - 1)), 0.0f), (float)(LL - 1));
        float fy = fminf(fmaxf((gys[pn] + 1.0f) * (0.5f * (LL - 1)), 0.0f), (float)(LL - 1));
        int x0 = (int)fx, y0 = (int)fy;
        float wx = fx - (float)x0, wy = fy - (float)y0;
        int x1 = min(x0 + 1, LL - 1), y1 = min(y0 + 1, LL - 1);
        w00[pn] = (1.f - wx) * (1.f - wy);
        w01[pn] = wx * (1.f - wy);
        w10[pn] = (1.f - wx) * wy;
        w11[pn] = wx * wy;
        const int jb = jg * J4 + cq;
        v00[pn] = jb + (y0 * LL + x0) * 4;
        v01[pn] = jb + (y0 * LL + x1) * 4;
        v10[pn] = jb + (y1 * LL + x0) * 4;
        v11[pn] = jb + (y1 * LL + x1) * 4;
    }

    /* out row in f32x4 units: p*288 + j*12 + pn*4 + cq, j = jt*4+jg */
    f32x4* outq = (f32x4*)out + (size_t)p * (NJ * 3 * CC / 4) + jg * 12 + cq;

#pragma unroll
    for (int pn = 0; pn < 3; ++pn) {
        const f32x4* bp = base4[pn];
        const float a00 = w00[pn], a01 = w01[pn], a10 = w10[pn], a11 = w11[pn];
        const int u00 = v00[pn], u01 = v01[pn], u10 = v10[pn], u11 = v11[pn];
#pragma unroll
        for (int jt = 0; jt < 6; ++jt) {
            const f32x4* bj = bp + (size_t)jt * 4 * J4;   /* SGPR base step */
            const f32x4 g00 = bj[u00];
            const f32x4 g01 = bj[u01];
            const f32x4 g10 = bj[u10];
            const f32x4 g11 = bj[u11];
            f32x4 r = a00 * g00 + a01 * g01 + a10 * g10 + a11 * g11;
            __builtin_nontemporal_store(r, &outq[jt * 48 + pn * 4]);  /* imm <= 3968 B */
        }
    }
}

extern "C" void kernel_launch(void* const* d_in, const int* in_sizes, int n_in,
                              void* d_out, int out_size, void* d_ws, size_t ws_size,
                              hipStream_t stream) {
    const int*   idp   = (const int*)d_in[0];
    const float* qp    = (const float*)d_in[1];
    const float* scale = (const float*)d_in[2];
    const float* px    = (const float*)d_in[3];
    const float* py    = (const float*)d_in[4];
    const float* pz    = (const float*)d_in[5];
    float* out = (float*)d_out;
    float* ws  = (float*)d_ws;

    /* ws layout: [0,300) partials, [384,390) mean+inv_scale */
    k_partial<<<RB, 256, 0, stream>>>(qp, ws);
    k_final<<<1, 256, 0, stream>>>(ws, scale, ws + 384);
    k_sample<<<NPTS / PPB, 256, 0, stream>>>(qp, px, py, pz, ws + 384, idp, out);
}